// Round 8
// baseline (1307.150 us; speedup 1.0000x reference)
//
#include <hip/hip_runtime.h>

// ---------------------------------------------------------------------------
// Round 7: R6 + coalesced epilogue stores (fix write-amplification).
//  R6 counters showed WRITE 468MB / FETCH 299MB: column-scattered 64B writes
//  caused RFO + double writebacks. Now: outputs -> regs -> barrier -> LDS
//  (f32, stride 260: 2 lanes/bank scatter) -> barrier -> row-major readback,
//  64B contiguous per thread = full 128B lines only.
//  Kept from R6: K-split (h-half MFMAs run while gather loads fly),
//  dotS/dotO per-node precompute, LDS f32 h-carry (no global hv re-read).
// ---------------------------------------------------------------------------

#define D_DIM 256
#define NNODE 32
#define NEDGE 992
#define EDGE_ROWS (128 * NEDGE)   // 126976
#define NODE_ROWS (128 * NNODE)   // 4096
#define BM 64
#define XH_OFF 0
#define HH_OFF 32768
#define HF_OFF 65536              // f32 carry buffer; reused as OUT (non-INIT)
#define OUT_OFF_INIT 32768        // OUT buffer for INIT variant
#define HF_STR 260                // padded f32 row stride (words)

typedef _Float16 half8 __attribute__((ext_vector_type(8)));
typedef __attribute__((ext_vector_type(4))) float f32x4;

__device__ __forceinline__ float sigf(float x) { return 1.0f / (1.0f + __expf(-x)); }
__device__ __forceinline__ float tanh_fast(float x) { return 2.0f / (1.0f + __expf(-2.0f * x)) - 1.0f; }
__device__ __forceinline__ float dot4(float4 a, float4 b) { return a.x*b.x + a.y*b.y + a.z*b.z + a.w*b.w; }

// Pack Wc[512][768] (rows 0-255 = WihT, 256-511 = WhhT) into MFMA B-fragment
// order, f16: ph[((ct*16+ks)*64+l)*8+j] = f16(Wc[ks*32+(l>>4)*8+j][ct*16+(l&15)])
__global__ __launch_bounds__(64) void pack_w(const float* __restrict__ Wih,
                                             const float* __restrict__ Whh,
                                             _Float16* __restrict__ ph) {
  const int ct = blockIdx.x;   // 0..47
  const int ks = blockIdx.y;   // 0..15
  const int l = threadIdx.x;   // 0..63
  const int col = ct * 16 + (l & 15);
  const int kb = ks * 32 + (l >> 4) * 8;
  const float* src = (kb < 256) ? (Wih + col * 256 + kb) : (Whh + col * 256 + (kb - 256));
  half8 v;
  #pragma unroll
  for (int j = 0; j < 8; ++j) v[j] = (_Float16)src[j];
  *(half8*)(ph + ((ct * 16 + ks) * 64 + l) * 8) = v;
}

template <bool INIT, bool GATES>
__global__ __launch_bounds__(1024, 4) void gru_mfma(
    const float* __restrict__ xsrc, const float* __restrict__ nhid,
    float* __restrict__ h, const _Float16* __restrict__ wp,
    const float* __restrict__ bih, const float* __restrict__ bhh,
    const float* __restrict__ wesb, const float* __restrict__ weob,
    const float* __restrict__ dotS, const float* __restrict__ dotO) {
  constexpr int LDSB = INIT ? (32768 + BM * HF_STR * 4) : (65536 + BM * HF_STR * 4);
  __shared__ __align__(16) unsigned char lds[LDSB];

  const int t = threadIdx.x;
  const int rb = blockIdx.x * BM;
  const int srow = t >> 4;       // staging: 16 threads per row
  const int skc = t & 15;
  const int w = t >> 6;          // compute: wave -> within-gate col-tile
  const int l = t & 63;
  const int lq = l >> 4;
  const int lr = l & 15;
  const int swm = (lr & 7) << 4;
  const int swz = (srow & 7) << 4;
  const int rowg = rb + srow;

  // ---------------- issue all global loads ----------------
  float4 pre[4];                 // h row (cold stream)
  float4 xa[4], xb[4];           // x source rows
  float dS = 0.f, dO = 0.f;
  const float* pxa;
  const float* pxb = nullptr;
  if constexpr (GATES) {
    const int b = rowg / NEDGE;
    const int e = rowg - b * NEDGE;
    const int si = e / 31;
    const int m = e - si * 31;
    const int ob = (m < si) ? m : (m + 1);
    pxa = nhid + (b * NNODE + si) * D_DIM;
    pxb = nhid + (b * NNODE + ob) * D_DIM;
    dS = dotS[b * NNODE + si];
    dO = dotO[b * NNODE + ob];
  } else {
    pxa = xsrc + rowg * D_DIM;
  }
  #pragma unroll
  for (int i = 0; i < 4; ++i) {
    const int k0 = (i >> 1) * 128 + skc * 8 + (i & 1) * 4;
    if constexpr (!INIT) pre[i] = *(const float4*)(h + rowg * D_DIM + k0);
    xa[i] = *(const float4*)(pxa + k0);
    if constexpr (GATES) xb[i] = *(const float4*)(pxb + k0);
  }

  float gs = 1.f, go = 0.f;
  if constexpr (!INIT) {
    // ---- h-half staging: f16 (MFMA) + f32 (carry) ----
    #pragma unroll
    for (int c = 0; c < 2; ++c) {
      half8 hh8;
      const float* f1 = (const float*)&pre[c * 2];
      #pragma unroll
      for (int j = 0; j < 8; ++j) hh8[j] = (_Float16)f1[j];
      *(half8*)(&lds[HH_OFF + ((srow * 512 + c * 256 + skc * 16) ^ swz)]) = hh8;
    }
    float* hfp = (float*)(lds + HF_OFF);
    #pragma unroll
    for (int i = 0; i < 4; ++i)
      *(float4*)(hfp + srow * HF_STR + (i >> 1) * 128 + skc * 8 + (i & 1) * 4) = pre[i];

    if constexpr (GATES) {
      // eh-part of the gate dots (ns/no parts precomputed in dotS/dotO)
      float pS = 0.f, pO = 0.f;
      #pragma unroll
      for (int i = 0; i < 4; ++i) {
        const int k0 = (i >> 1) * 128 + skc * 8 + (i & 1) * 4;
        pS += dot4(pre[i], *(const float4*)(wesb + k0));
        pO += dot4(pre[i], *(const float4*)(weob + k0));
      }
      #pragma unroll
      for (int mm = 1; mm < 16; mm <<= 1) {
        pS += __shfl_xor(pS, mm, 16);
        pO += __shfl_xor(pO, mm, 16);
      }
      gs = sigf(dS + pS);
      go = sigf(dO + pO);
    }
  }

  const f32x4 zz = {0.f, 0.f, 0.f, 0.f};
  f32x4 acc_r[4] = {zz, zz, zz, zz};
  f32x4 acc_z[4] = {zz, zz, zz, zz};
  f32x4 acc_nx[4] = {zz, zz, zz, zz};
  f32x4 acc_nh[4] = {zz, zz, zz, zz};

  auto KS = [&](int abase, int ksgl, int ksg, f32x4 (&accn)[4]) {
    half8 ah[4];
    #pragma unroll
    for (int rf = 0; rf < 4; ++rf)
      ah[rf] = *(const half8*)(&lds[abase + (((rf * 16 + lr) * 512 + ksgl * 64 + lq * 16) ^ swm)]);
    const half8 br_ = *(const half8*)(wp + (((0 * 16 + w) * 16 + ksg) * 64 + l) * 8);
    const half8 bz_ = *(const half8*)(wp + (((1 * 16 + w) * 16 + ksg) * 64 + l) * 8);
    const half8 bn_ = *(const half8*)(wp + (((2 * 16 + w) * 16 + ksg) * 64 + l) * 8);
    #pragma unroll
    for (int rf = 0; rf < 4; ++rf)
      acc_r[rf] = __builtin_amdgcn_mfma_f32_16x16x32_f16(ah[rf], br_, acc_r[rf], 0, 0, 0);
    #pragma unroll
    for (int rf = 0; rf < 4; ++rf)
      acc_z[rf] = __builtin_amdgcn_mfma_f32_16x16x32_f16(ah[rf], bz_, acc_z[rf], 0, 0, 0);
    #pragma unroll
    for (int rf = 0; rf < 4; ++rf)
      accn[rf] = __builtin_amdgcn_mfma_f32_16x16x32_f16(ah[rf], bn_, accn[rf], 0, 0, 0);
  };

  if constexpr (!INIT) {
    __syncthreads();
    // 96 h-half MFMAs; xa/xb loads still landing underneath
    #pragma unroll
    for (int ksgl = 0; ksgl < 8; ++ksgl) KS(HH_OFF, ksgl, 8 + ksgl, acc_nh);
    // gate-combine x, cvt, write x-half
    #pragma unroll
    for (int c = 0; c < 2; ++c) {
      half8 hx;
      #pragma unroll
      for (int pq = 0; pq < 2; ++pq) {
        const float* fa = (const float*)&xa[c * 2 + pq];
        const float* fb = (const float*)&xb[c * 2 + pq];
        #pragma unroll
        for (int j = 0; j < 4; ++j) {
          float v = GATES ? (gs * fa[j] + go * fb[j]) : fa[j];
          hx[pq * 4 + j] = (_Float16)v;
        }
      }
      *(half8*)(&lds[XH_OFF + ((srow * 512 + c * 256 + skc * 16) ^ swz)]) = hx;
    }
    __syncthreads();
  } else {
    #pragma unroll
    for (int c = 0; c < 2; ++c) {
      half8 hx;
      const float* f0 = (const float*)&xa[c * 2];
      #pragma unroll
      for (int j = 0; j < 8; ++j) hx[j] = (_Float16)f0[j];
      *(half8*)(&lds[XH_OFF + ((srow * 512 + c * 256 + skc * 16) ^ swz)]) = hx;
    }
    __syncthreads();
  }

  // 96 x-half MFMAs
  #pragma unroll
  for (int ksgl = 0; ksgl < 8; ++ksgl) KS(XH_OFF, ksgl, ksgl, acc_nx);

  // ---------------- epilogue: exact-f32 GRU combine ----------------
  const float* hfp = (const float*)(lds + HF_OFF);
  const int col = w * 16 + lr;
  {
    const float br = bih[col] + bhh[col];
    const float bz = bih[256 + col] + bhh[256 + col];
    const float bnx = bih[512 + col];
    const float bnh = bhh[512 + col];
    f32x4 outv[4];
    #pragma unroll
    for (int rf = 0; rf < 4; ++rf) {
      #pragma unroll
      for (int q = 0; q < 4; ++q) {
        const int rowl = rf * 16 + lq * 4 + q;
        const float r = sigf(acc_r[rf][q] + br);
        const float z = sigf(acc_z[rf][q] + bz);
        const float n = tanh_fast(acc_nx[rf][q] + bnx + r * (acc_nh[rf][q] + bnh));
        float hv = 0.0f;
        if constexpr (!INIT) hv = hfp[rowl * HF_STR + col];
        outv[rf][q] = (1.0f - z) * n + z * hv;
      }
    }
    // scatter to LDS (full-line-coalescing staging), then row-major readback
    __syncthreads();  // non-INIT: all hv reads done before overwrite
    float* outp = (float*)(lds + (INIT ? OUT_OFF_INIT : HF_OFF));
    #pragma unroll
    for (int rf = 0; rf < 4; ++rf) {
      #pragma unroll
      for (int q = 0; q < 4; ++q)
        outp[(rf * 16 + lq * 4 + q) * HF_STR + col] = outv[rf][q];
    }
  }
  __syncthreads();
  {
    const float* outp = (const float*)(lds + (INIT ? OUT_OFF_INIT : HF_OFF));
    float* dst = h + (rb + srow) * D_DIM + skc * 16;
    #pragma unroll
    for (int j = 0; j < 4; ++j)
      *(float4*)(dst + j * 4) = *(const float4*)(outp + srow * HF_STR + skc * 16 + j * 4);
  }
}

// per node row: dotA = nh.wnp[0:256], dotS = nh.wes[0:256], dotO = nh.weo[0:256]
__global__ __launch_bounds__(256) void dot3_kernel(
    const float* __restrict__ nh, const float* __restrict__ wnp,
    const float* __restrict__ wes, const float* __restrict__ weo,
    float* __restrict__ dA, float* __restrict__ dS, float* __restrict__ dO) {
  const int r = blockIdx.x * 4 + (threadIdx.x >> 6);
  const int l = threadIdx.x & 63;
  const float4 v = ((const float4*)(nh + r * D_DIM))[l];
  float p1 = dot4(v, ((const float4*)wnp)[l]);
  float p2 = dot4(v, ((const float4*)wes)[l]);
  float p3 = dot4(v, ((const float4*)weo)[l]);
  #pragma unroll
  for (int mm = 32; mm > 0; mm >>= 1) {
    p1 += __shfl_xor(p1, mm, 64);
    p2 += __shfl_xor(p2, mm, 64);
    p3 += __shfl_xor(p3, mm, 64);
  }
  if (l == 0) { dA[r] = p1; dS[r] = p2; dO[r] = p3; }
}

// node_msg[b,n] = sum over 62 incident edges of gN*eh,
// gN = sig(dotA[b,sub] + eh . w_node_pool[256:512]) computed inline.
__global__ __launch_bounds__(256) void node_msg_kernel(
    const float* __restrict__ eh, const float* __restrict__ wnp,
    const float* __restrict__ dotA, float* __restrict__ nmsg) {
  __shared__ float sh[3][256];
  const int nr = blockIdx.x;  // 0..4095
  const int b = nr >> 5;
  const int n = nr & 31;
  const int wv = threadIdx.x >> 6;
  const int l = threadIdx.x & 63;
  const int base = b * NEDGE;
  const float4 w1b = ((const float4*)(wnp + 256))[l];

  float4 acc = {0.f, 0.f, 0.f, 0.f};
  for (int k = wv; k < 62; k += 4) {
    int e, sub;
    if (k < 31) {             // out-edge (n -> *)
      e = base + n * 31 + k;
      sub = n;
    } else {                  // in-edge (i -> n)
      int i = k - 31;
      const int ip = (i < n) ? i : (i + 1);
      e = base + ip * 31 + ((n < ip) ? n : (n - 1));
      sub = ip;
    }
    const float4 ev = ((const float4*)(eh + e * D_DIM))[l];
    float p = dot4(ev, w1b);
    #pragma unroll
    for (int mm = 32; mm > 0; mm >>= 1) p += __shfl_xor(p, mm, 64);
    const float gN = sigf(dotA[b * NNODE + sub] + p);
    acc.x += gN * ev.x; acc.y += gN * ev.y; acc.z += gN * ev.z; acc.w += gN * ev.w;
  }
  if (wv > 0) *(float4*)(&sh[wv - 1][l * 4]) = acc;
  __syncthreads();
  if (wv == 0) {
    #pragma unroll
    for (int v = 0; v < 3; ++v) {
      const float4 o = *(const float4*)(&sh[v][l * 4]);
      acc.x += o.x; acc.y += o.y; acc.z += o.z; acc.w += o.w;
    }
    *(float4*)(nmsg + nr * D_DIM + l * 4) = acc;
  }
}

extern "C" void kernel_launch(void* const* d_in, const int* in_sizes, int n_in,
                              void* d_out, int out_size, void* d_ws, size_t ws_size,
                              hipStream_t stream) {
  const float* node_latents = (const float*)d_in[0];
  const float* edge_latents = (const float*)d_in[1];
  const float* node_Wih = (const float*)d_in[2];
  const float* node_Whh = (const float*)d_in[3];
  const float* node_bih = (const float*)d_in[4];
  const float* node_bhh = (const float*)d_in[5];
  const float* edge_Wih = (const float*)d_in[6];
  const float* edge_Whh = (const float*)d_in[7];
  const float* edge_bih = (const float*)d_in[8];
  const float* edge_bhh = (const float*)d_in[9];
  const float* w_node_pool = (const float*)d_in[10];
  const float* w_edge_sub = (const float*)d_in[11];
  const float* w_edge_obj = (const float*)d_in[12];

  float* nh = (float*)d_out;
  float* eh = (float*)d_out + NODE_ROWS * D_DIM;

  const int WPLANE = 48 * 16 * 64 * 8;  // 393216 f16 = 768KB
  _Float16* ph_n = (_Float16*)d_ws;
  _Float16* ph_e = ph_n + WPLANE;
  float* fw = (float*)(ph_e + WPLANE);
  float* dotA = fw; fw += NODE_ROWS;
  float* dotS = fw; fw += NODE_ROWS;
  float* dotO = fw; fw += NODE_ROWS;
  float* node_msg = fw; fw += NODE_ROWS * D_DIM;  // total ~5.7 MB

  dim3 pg(48, 16);
  pack_w<<<pg, 64, 0, stream>>>(node_Wih, node_Whh, ph_n);
  pack_w<<<pg, 64, 0, stream>>>(edge_Wih, edge_Whh, ph_e);

  gru_mfma<true, false><<<NODE_ROWS / BM, 1024, 0, stream>>>(
      node_latents, nullptr, nh, ph_n, node_bih, node_bhh,
      nullptr, nullptr, nullptr, nullptr);
  gru_mfma<true, false><<<EDGE_ROWS / BM, 1024, 0, stream>>>(
      edge_latents, nullptr, eh, ph_e, edge_bih, edge_bhh,
      nullptr, nullptr, nullptr, nullptr);

  for (int it = 0; it < 3; ++it) {
    dot3_kernel<<<NODE_ROWS / 4, 256, 0, stream>>>(nh, w_node_pool, w_edge_sub,
                                                   w_edge_obj, dotA, dotS, dotO);
    node_msg_kernel<<<NODE_ROWS, 256, 0, stream>>>(eh, w_node_pool, dotA, node_msg);
    gru_mfma<false, true><<<EDGE_ROWS / BM, 1024, 0, stream>>>(
        nullptr, nh, eh, ph_e, edge_bih, edge_bhh,
        w_edge_sub + 256, w_edge_obj + 256, dotS, dotO);
    gru_mfma<false, false><<<NODE_ROWS / BM, 1024, 0, stream>>>(
        node_msg, nullptr, nh, ph_n, node_bih, node_bhh,
        nullptr, nullptr, nullptr, nullptr);
  }
}

// Round 9
// 1164.607 us; speedup vs baseline: 1.1224x; 1.1224x over previous
//
#include <hip/hip_runtime.h>

// ---------------------------------------------------------------------------
// Round 8: fix R6/R7 scratch-spill traffic (WRITE 476MB was spills, not RFO).
//  Register discipline: never hold loaded payload across an MFMA phase.
//   stage1: load pre(h row) -> LDS f16 + LDS f32 carry + gate dots (pre dies;
//           only gs/go live on). barrier.
//   96 h-half MFMAs.
//   combine: load xa/xb (nhid, L2-hot) -> gs*xa+go*xb -> cvt -> LDS. barrier.
//   96 x-half MFMAs.
//   epilogue: f32 combine (hv from LDS carry) -> LDS restage -> coalesced
//             full-line stores (R7 mechanism, now unmasked by spills).
//  Kept: dotS/dotO per-node precompute, node_msg gN fusion.
// ---------------------------------------------------------------------------

#define D_DIM 256
#define NNODE 32
#define NEDGE 992
#define EDGE_ROWS (128 * NEDGE)   // 126976
#define NODE_ROWS (128 * NNODE)   // 4096
#define BM 64
#define XH_OFF 0
#define HH_OFF 32768
#define HF_OFF 65536              // f32 carry; reused as OUT stage (non-INIT)
#define OUT_OFF_INIT 32768        // OUT stage for INIT variant
#define HF_STR 260                // padded f32 row stride (words)

typedef _Float16 half8 __attribute__((ext_vector_type(8)));
typedef __attribute__((ext_vector_type(4))) float f32x4;

__device__ __forceinline__ float sigf(float x) { return 1.0f / (1.0f + __expf(-x)); }
__device__ __forceinline__ float tanh_fast(float x) { return 2.0f / (1.0f + __expf(-2.0f * x)) - 1.0f; }
__device__ __forceinline__ float dot4(float4 a, float4 b) { return a.x*b.x + a.y*b.y + a.z*b.z + a.w*b.w; }

// Pack Wc[512][768] (rows 0-255 = WihT, 256-511 = WhhT) into MFMA B-fragment
// order, f16: ph[((ct*16+ks)*64+l)*8+j] = f16(Wc[ks*32+(l>>4)*8+j][ct*16+(l&15)])
__global__ __launch_bounds__(64) void pack_w(const float* __restrict__ Wih,
                                             const float* __restrict__ Whh,
                                             _Float16* __restrict__ ph) {
  const int ct = blockIdx.x;   // 0..47
  const int ks = blockIdx.y;   // 0..15
  const int l = threadIdx.x;   // 0..63
  const int col = ct * 16 + (l & 15);
  const int kb = ks * 32 + (l >> 4) * 8;
  const float* src = (kb < 256) ? (Wih + col * 256 + kb) : (Whh + col * 256 + (kb - 256));
  half8 v;
  #pragma unroll
  for (int j = 0; j < 8; ++j) v[j] = (_Float16)src[j];
  *(half8*)(ph + ((ct * 16 + ks) * 64 + l) * 8) = v;
}

template <bool INIT, bool GATES>
__global__ __launch_bounds__(1024, 4) void gru_mfma(
    const float* __restrict__ xsrc, const float* __restrict__ nhid,
    float* __restrict__ h, const _Float16* __restrict__ wp,
    const float* __restrict__ bih, const float* __restrict__ bhh,
    const float* __restrict__ wesb, const float* __restrict__ weob,
    const float* __restrict__ dotS, const float* __restrict__ dotO) {
  constexpr int LDSB = INIT ? (32768 + BM * HF_STR * 4) : (65536 + BM * HF_STR * 4);
  __shared__ __align__(16) unsigned char lds[LDSB];

  const int t = threadIdx.x;
  const int rb = blockIdx.x * BM;
  const int srow = t >> 4;       // staging: 16 threads per row
  const int skc = t & 15;
  const int w = t >> 6;          // compute: wave -> within-gate col-tile
  const int l = t & 63;
  const int lq = l >> 4;
  const int lr = l & 15;
  const int swm = (lr & 7) << 4;
  const int swz = (srow & 7) << 4;
  const int rowg = rb + srow;

  // ---- x-source pointers (cheap scalars, no data loaded yet) ----
  const float* pxa;
  const float* pxb = nullptr;
  float dS = 0.f, dO = 0.f;
  if constexpr (GATES) {
    const int b = rowg / NEDGE;
    const int e = rowg - b * NEDGE;
    const int si = e / 31;
    const int m = e - si * 31;
    const int ob = (m < si) ? m : (m + 1);
    pxa = nhid + (b * NNODE + si) * D_DIM;
    pxb = nhid + (b * NNODE + ob) * D_DIM;
    dS = dotS[b * NNODE + si];
    dO = dotO[b * NNODE + ob];
  } else {
    pxa = xsrc + rowg * D_DIM;
  }

  float gs = 1.f, go = 0.f;
  if constexpr (!INIT) {
    // ---- stage 1: load h row, consume fully (f16 LDS + f32 carry + dots) ----
    float4 pre[4];
    #pragma unroll
    for (int i = 0; i < 4; ++i)
      pre[i] = *(const float4*)(h + rowg * D_DIM + (i >> 1) * 128 + skc * 8 + (i & 1) * 4);
    #pragma unroll
    for (int c = 0; c < 2; ++c) {
      half8 hh8;
      const float* f1 = (const float*)&pre[c * 2];
      #pragma unroll
      for (int j = 0; j < 8; ++j) hh8[j] = (_Float16)f1[j];
      *(half8*)(&lds[HH_OFF + ((srow * 512 + c * 256 + skc * 16) ^ swz)]) = hh8;
    }
    float* hfp = (float*)(lds + HF_OFF);
    #pragma unroll
    for (int i = 0; i < 4; ++i)
      *(float4*)(hfp + srow * HF_STR + (i >> 1) * 128 + skc * 8 + (i & 1) * 4) = pre[i];
    if constexpr (GATES) {
      float pS = 0.f, pO = 0.f;
      #pragma unroll
      for (int i = 0; i < 4; ++i) {
        const int k0 = (i >> 1) * 128 + skc * 8 + (i & 1) * 4;
        pS += dot4(pre[i], *(const float4*)(wesb + k0));
        pO += dot4(pre[i], *(const float4*)(weob + k0));
      }
      #pragma unroll
      for (int mm = 1; mm < 16; mm <<= 1) {
        pS += __shfl_xor(pS, mm, 16);
        pO += __shfl_xor(pO, mm, 16);
      }
      gs = sigf(dS + pS);
      go = sigf(dO + pO);
    }
  }

  const f32x4 zz = {0.f, 0.f, 0.f, 0.f};
  f32x4 acc_r[4] = {zz, zz, zz, zz};
  f32x4 acc_z[4] = {zz, zz, zz, zz};
  f32x4 acc_nx[4] = {zz, zz, zz, zz};
  f32x4 acc_nh[4] = {zz, zz, zz, zz};

  auto KS = [&](int abase, int ksgl, int ksg, f32x4 (&accn)[4]) {
    half8 ah[4];
    #pragma unroll
    for (int rf = 0; rf < 4; ++rf)
      ah[rf] = *(const half8*)(&lds[abase + (((rf * 16 + lr) * 512 + ksgl * 64 + lq * 16) ^ swm)]);
    const half8 br_ = *(const half8*)(wp + (((0 * 16 + w) * 16 + ksg) * 64 + l) * 8);
    const half8 bz_ = *(const half8*)(wp + (((1 * 16 + w) * 16 + ksg) * 64 + l) * 8);
    const half8 bn_ = *(const half8*)(wp + (((2 * 16 + w) * 16 + ksg) * 64 + l) * 8);
    #pragma unroll
    for (int rf = 0; rf < 4; ++rf)
      acc_r[rf] = __builtin_amdgcn_mfma_f32_16x16x32_f16(ah[rf], br_, acc_r[rf], 0, 0, 0);
    #pragma unroll
    for (int rf = 0; rf < 4; ++rf)
      acc_z[rf] = __builtin_amdgcn_mfma_f32_16x16x32_f16(ah[rf], bz_, acc_z[rf], 0, 0, 0);
    #pragma unroll
    for (int rf = 0; rf < 4; ++rf)
      accn[rf] = __builtin_amdgcn_mfma_f32_16x16x32_f16(ah[rf], bn_, accn[rf], 0, 0, 0);
  };

  if constexpr (!INIT) {
    __syncthreads();
    // 96 h-half MFMAs (only gs/go carried live besides acc)
    #pragma unroll
    for (int ksgl = 0; ksgl < 8; ++ksgl) KS(HH_OFF, ksgl, 8 + ksgl, acc_nh);
  }

  // ---- combine: load x rows (L2-hot), consume immediately ----
  {
    #pragma unroll
    for (int c = 0; c < 2; ++c) {
      half8 hx;
      #pragma unroll
      for (int pq = 0; pq < 2; ++pq) {
        const int k0 = c * 128 + skc * 8 + pq * 4;
        const float4 a = *(const float4*)(pxa + k0);
        float4 v = a;
        if constexpr (GATES) {
          const float4 b4 = *(const float4*)(pxb + k0);
          v.x = gs * a.x + go * b4.x; v.y = gs * a.y + go * b4.y;
          v.z = gs * a.z + go * b4.z; v.w = gs * a.w + go * b4.w;
        }
        hx[pq * 4 + 0] = (_Float16)v.x; hx[pq * 4 + 1] = (_Float16)v.y;
        hx[pq * 4 + 2] = (_Float16)v.z; hx[pq * 4 + 3] = (_Float16)v.w;
      }
      *(half8*)(&lds[XH_OFF + ((srow * 512 + c * 256 + skc * 16) ^ swz)]) = hx;
    }
  }
  __syncthreads();

  // 96 x-half MFMAs
  #pragma unroll
  for (int ksgl = 0; ksgl < 8; ++ksgl) KS(XH_OFF, ksgl, ksgl, acc_nx);

  // ---------------- epilogue: exact-f32 GRU combine ----------------
  const float* hfp = (const float*)(lds + HF_OFF);
  const int col = w * 16 + lr;
  {
    const float br = bih[col] + bhh[col];
    const float bz = bih[256 + col] + bhh[256 + col];
    const float bnx = bih[512 + col];
    const float bnh = bhh[512 + col];
    f32x4 outv[4];
    #pragma unroll
    for (int rf = 0; rf < 4; ++rf) {
      #pragma unroll
      for (int q = 0; q < 4; ++q) {
        const int rowl = rf * 16 + lq * 4 + q;
        const float r = sigf(acc_r[rf][q] + br);
        const float z = sigf(acc_z[rf][q] + bz);
        const float n = tanh_fast(acc_nx[rf][q] + bnx + r * (acc_nh[rf][q] + bnh));
        float hv = 0.0f;
        if constexpr (!INIT) hv = hfp[rowl * HF_STR + col];
        outv[rf][q] = (1.0f - z) * n + z * hv;
      }
    }
    __syncthreads();  // non-INIT: all hv reads done before carry-buffer reuse
    float* outp = (float*)(lds + (INIT ? OUT_OFF_INIT : HF_OFF));
    #pragma unroll
    for (int rf = 0; rf < 4; ++rf) {
      #pragma unroll
      for (int q = 0; q < 4; ++q)
        outp[(rf * 16 + lq * 4 + q) * HF_STR + col] = outv[rf][q];
    }
  }
  __syncthreads();
  {
    const float* outp = (const float*)(lds + (INIT ? OUT_OFF_INIT : HF_OFF));
    float* dst = h + (rb + srow) * D_DIM + skc * 16;
    #pragma unroll
    for (int j = 0; j < 4; ++j)
      *(float4*)(dst + j * 4) = *(const float4*)(outp + srow * HF_STR + skc * 16 + j * 4);
  }
}

// per node row: dotA = nh.wnp[0:256], dotS = nh.wes[0:256], dotO = nh.weo[0:256]
__global__ __launch_bounds__(256) void dot3_kernel(
    const float* __restrict__ nh, const float* __restrict__ wnp,
    const float* __restrict__ wes, const float* __restrict__ weo,
    float* __restrict__ dA, float* __restrict__ dS, float* __restrict__ dO) {
  const int r = blockIdx.x * 4 + (threadIdx.x >> 6);
  const int l = threadIdx.x & 63;
  const float4 v = ((const float4*)(nh + r * D_DIM))[l];
  float p1 = dot4(v, ((const float4*)wnp)[l]);
  float p2 = dot4(v, ((const float4*)wes)[l]);
  float p3 = dot4(v, ((const float4*)weo)[l]);
  #pragma unroll
  for (int mm = 32; mm > 0; mm >>= 1) {
    p1 += __shfl_xor(p1, mm, 64);
    p2 += __shfl_xor(p2, mm, 64);
    p3 += __shfl_xor(p3, mm, 64);
  }
  if (l == 0) { dA[r] = p1; dS[r] = p2; dO[r] = p3; }
}

// node_msg[b,n] = sum over 62 incident edges of gN*eh,
// gN = sig(dotA[b,sub] + eh . w_node_pool[256:512]) computed inline.
__global__ __launch_bounds__(256) void node_msg_kernel(
    const float* __restrict__ eh, const float* __restrict__ wnp,
    const float* __restrict__ dotA, float* __restrict__ nmsg) {
  __shared__ float sh[3][256];
  const int nr = blockIdx.x;  // 0..4095
  const int b = nr >> 5;
  const int n = nr & 31;
  const int wv = threadIdx.x >> 6;
  const int l = threadIdx.x & 63;
  const int base = b * NEDGE;
  const float4 w1b = ((const float4*)(wnp + 256))[l];

  float4 acc = {0.f, 0.f, 0.f, 0.f};
  for (int k = wv; k < 62; k += 4) {
    int e, sub;
    if (k < 31) {             // out-edge (n -> *)
      e = base + n * 31 + k;
      sub = n;
    } else {                  // in-edge (i -> n)
      int i = k - 31;
      const int ip = (i < n) ? i : (i + 1);
      e = base + ip * 31 + ((n < ip) ? n : (n - 1));
      sub = ip;
    }
    const float4 ev = ((const float4*)(eh + e * D_DIM))[l];
    float p = dot4(ev, w1b);
    #pragma unroll
    for (int mm = 32; mm > 0; mm >>= 1) p += __shfl_xor(p, mm, 64);
    const float gN = sigf(dotA[b * NNODE + sub] + p);
    acc.x += gN * ev.x; acc.y += gN * ev.y; acc.z += gN * ev.z; acc.w += gN * ev.w;
  }
  if (wv > 0) *(float4*)(&sh[wv - 1][l * 4]) = acc;
  __syncthreads();
  if (wv == 0) {
    #pragma unroll
    for (int v = 0; v < 3; ++v) {
      const float4 o = *(const float4*)(&sh[v][l * 4]);
      acc.x += o.x; acc.y += o.y; acc.z += o.z; acc.w += o.w;
    }
    *(float4*)(nmsg + nr * D_DIM + l * 4) = acc;
  }
}

extern "C" void kernel_launch(void* const* d_in, const int* in_sizes, int n_in,
                              void* d_out, int out_size, void* d_ws, size_t ws_size,
                              hipStream_t stream) {
  const float* node_latents = (const float*)d_in[0];
  const float* edge_latents = (const float*)d_in[1];
  const float* node_Wih = (const float*)d_in[2];
  const float* node_Whh = (const float*)d_in[3];
  const float* node_bih = (const float*)d_in[4];
  const float* node_bhh = (const float*)d_in[5];
  const float* edge_Wih = (const float*)d_in[6];
  const float* edge_Whh = (const float*)d_in[7];
  const float* edge_bih = (const float*)d_in[8];
  const float* edge_bhh = (const float*)d_in[9];
  const float* w_node_pool = (const float*)d_in[10];
  const float* w_edge_sub = (const float*)d_in[11];
  const float* w_edge_obj = (const float*)d_in[12];

  float* nh = (float*)d_out;
  float* eh = (float*)d_out + NODE_ROWS * D_DIM;

  const int WPLANE = 48 * 16 * 64 * 8;  // 393216 f16 = 768KB
  _Float16* ph_n = (_Float16*)d_ws;
  _Float16* ph_e = ph_n + WPLANE;
  float* fw = (float*)(ph_e + WPLANE);
  float* dotA = fw; fw += NODE_ROWS;
  float* dotS = fw; fw += NODE_ROWS;
  float* dotO = fw; fw += NODE_ROWS;
  float* node_msg = fw; fw += NODE_ROWS * D_DIM;  // total ~5.7 MB

  dim3 pg(48, 16);
  pack_w<<<pg, 64, 0, stream>>>(node_Wih, node_Whh, ph_n);
  pack_w<<<pg, 64, 0, stream>>>(edge_Wih, edge_Whh, ph_e);

  gru_mfma<true, false><<<NODE_ROWS / BM, 1024, 0, stream>>>(
      node_latents, nullptr, nh, ph_n, node_bih, node_bhh,
      nullptr, nullptr, nullptr, nullptr);
  gru_mfma<true, false><<<EDGE_ROWS / BM, 1024, 0, stream>>>(
      edge_latents, nullptr, eh, ph_e, edge_bih, edge_bhh,
      nullptr, nullptr, nullptr, nullptr);

  for (int it = 0; it < 3; ++it) {
    dot3_kernel<<<NODE_ROWS / 4, 256, 0, stream>>>(nh, w_node_pool, w_edge_sub,
                                                   w_edge_obj, dotA, dotS, dotO);
    node_msg_kernel<<<NODE_ROWS, 256, 0, stream>>>(eh, w_node_pool, dotA, node_msg);
    gru_mfma<false, true><<<EDGE_ROWS / BM, 1024, 0, stream>>>(
        nullptr, nh, eh, ph_e, edge_bih, edge_bhh,
        w_edge_sub + 256, w_edge_obj + 256, dotS, dotO);
    gru_mfma<false, false><<<NODE_ROWS / BM, 1024, 0, stream>>>(
        node_msg, nullptr, nh, ph_n, node_bih, node_bhh,
        nullptr, nullptr, nullptr, nullptr);
  }
}

// Round 10
// 862.296 us; speedup vs baseline: 1.5159x; 1.3506x over previous
//
#include <hip/hip_runtime.h>

// ---------------------------------------------------------------------------
// Round 9: R8 minus the spill-inducing epilogue machinery.
//  Diff vs R4 (last clean-traffic kernel: WRITE 162MB / FETCH 148MB / 199us):
//   + K-split h-first (96 h-MFMAs run while gather xa/xb loads are in flight)
//   + dotS/dotO per-node precompute (gate dot = eh-part only)
//  Diff vs R8 (dirty: WRITE 373MB = ~30 f32/thread scratch spill):
//   - NO LDS f32 h-carry, NO outv[16]+LDS restage: epilogue is R4-exact
//     (per-rf immediate compute+store, global hv re-read -> L2-hot).
//  LDS 64KB (non-INIT) / 32KB (INIT).
// ---------------------------------------------------------------------------

#define D_DIM 256
#define NNODE 32
#define NEDGE 992
#define EDGE_ROWS (128 * NEDGE)   // 126976
#define NODE_ROWS (128 * NNODE)   // 4096
#define BM 64
#define XH_OFF 0                   // x half: bytes [0,512) within a 1KB row
#define HH_OFF 512                 // h half: bytes [512,1024)

typedef _Float16 half8 __attribute__((ext_vector_type(8)));
typedef __attribute__((ext_vector_type(4))) float f32x4;

__device__ __forceinline__ float sigf(float x) { return 1.0f / (1.0f + __expf(-x)); }
__device__ __forceinline__ float tanh_fast(float x) { return 2.0f / (1.0f + __expf(-2.0f * x)) - 1.0f; }
__device__ __forceinline__ float dot4(float4 a, float4 b) { return a.x*b.x + a.y*b.y + a.z*b.z + a.w*b.w; }

// Pack Wc[512][768] (rows 0-255 = WihT, 256-511 = WhhT) into MFMA B-fragment
// order, f16: ph[((ct*16+ks)*64+l)*8+j] = f16(Wc[ks*32+(l>>4)*8+j][ct*16+(l&15)])
__global__ __launch_bounds__(64) void pack_w(const float* __restrict__ Wih,
                                             const float* __restrict__ Whh,
                                             _Float16* __restrict__ ph) {
  const int ct = blockIdx.x;   // 0..47
  const int ks = blockIdx.y;   // 0..15
  const int l = threadIdx.x;   // 0..63
  const int col = ct * 16 + (l & 15);
  const int kb = ks * 32 + (l >> 4) * 8;
  const float* src = (kb < 256) ? (Wih + col * 256 + kb) : (Whh + col * 256 + (kb - 256));
  half8 v;
  #pragma unroll
  for (int j = 0; j < 8; ++j) v[j] = (_Float16)src[j];
  *(half8*)(ph + ((ct * 16 + ks) * 64 + l) * 8) = v;
}

template <bool INIT, bool GATES>
__global__ __launch_bounds__(1024, 4) void gru_mfma(
    const float* __restrict__ xsrc, const float* __restrict__ nhid,
    float* __restrict__ h, const _Float16* __restrict__ wp,
    const float* __restrict__ bih, const float* __restrict__ bhh,
    const float* __restrict__ wesb, const float* __restrict__ weob,
    const float* __restrict__ dotS, const float* __restrict__ dotO) {
  constexpr int RSTR = INIT ? 512 : 1024;   // LDS row stride (bytes)
  __shared__ __align__(16) unsigned char lds[BM * RSTR];

  const int t = threadIdx.x;
  const int rb = blockIdx.x * BM;
  const int srow = t >> 4;       // staging: 16 threads per row
  const int skc = t & 15;
  const int w = t >> 6;          // compute: wave -> within-gate col-tile
  const int l = t & 63;
  const int lq = l >> 4;
  const int lr = l & 15;
  const int swm = (lr & 7) << 4;
  const int swz = (srow & 7) << 4;
  const int rowg = rb + srow;

  // ---- x-source pointers (cheap scalars) ----
  const float* pxa;
  const float* pxb = nullptr;
  float dS = 0.f, dO = 0.f;
  if constexpr (GATES) {
    const int b = rowg / NEDGE;
    const int e = rowg - b * NEDGE;
    const int si = e / 31;
    const int m = e - si * 31;
    const int ob = (m < si) ? m : (m + 1);
    pxa = nhid + (b * NNODE + si) * D_DIM;
    pxb = nhid + (b * NNODE + ob) * D_DIM;
    dS = dotS[b * NNODE + si];
    dO = dotO[b * NNODE + ob];
  } else {
    pxa = xsrc + rowg * D_DIM;
  }

  float gs = 1.f, go = 0.f;
  if constexpr (!INIT) {
    // ---- stage 1: load h row, consume fully (f16 LDS + gate dots) ----
    float4 pre[4];
    #pragma unroll
    for (int i = 0; i < 4; ++i)
      pre[i] = *(const float4*)(h + rowg * D_DIM + (i >> 1) * 128 + skc * 8 + (i & 1) * 4);
    #pragma unroll
    for (int c = 0; c < 2; ++c) {
      half8 hh8;
      const float* f1 = (const float*)&pre[c * 2];
      #pragma unroll
      for (int j = 0; j < 8; ++j) hh8[j] = (_Float16)f1[j];
      *(half8*)(&lds[(srow * RSTR + HH_OFF + c * 256 + skc * 16) ^ swz]) = hh8;
    }
    if constexpr (GATES) {
      float pS = 0.f, pO = 0.f;
      #pragma unroll
      for (int i = 0; i < 4; ++i) {
        const int k0 = (i >> 1) * 128 + skc * 8 + (i & 1) * 4;
        pS += dot4(pre[i], *(const float4*)(wesb + k0));
        pO += dot4(pre[i], *(const float4*)(weob + k0));
      }
      #pragma unroll
      for (int mm = 1; mm < 16; mm <<= 1) {
        pS += __shfl_xor(pS, mm, 16);
        pO += __shfl_xor(pO, mm, 16);
      }
      gs = sigf(dS + pS);
      go = sigf(dO + pO);
    }
  }

  const f32x4 zz = {0.f, 0.f, 0.f, 0.f};
  f32x4 acc_r[4] = {zz, zz, zz, zz};
  f32x4 acc_z[4] = {zz, zz, zz, zz};
  f32x4 acc_nx[4] = {zz, zz, zz, zz};
  f32x4 acc_nh[4] = {zz, zz, zz, zz};

  auto KS = [&](int hoff, int ksgl, int ksg, f32x4 (&accn)[4]) {
    half8 ah[4];
    #pragma unroll
    for (int rf = 0; rf < 4; ++rf)
      ah[rf] = *(const half8*)(&lds[((rf * 16 + lr) * RSTR + hoff + ksgl * 64 + lq * 16) ^ swm]);
    const half8 br_ = *(const half8*)(wp + (((0 * 16 + w) * 16 + ksg) * 64 + l) * 8);
    const half8 bz_ = *(const half8*)(wp + (((1 * 16 + w) * 16 + ksg) * 64 + l) * 8);
    const half8 bn_ = *(const half8*)(wp + (((2 * 16 + w) * 16 + ksg) * 64 + l) * 8);
    #pragma unroll
    for (int rf = 0; rf < 4; ++rf)
      acc_r[rf] = __builtin_amdgcn_mfma_f32_16x16x32_f16(ah[rf], br_, acc_r[rf], 0, 0, 0);
    #pragma unroll
    for (int rf = 0; rf < 4; ++rf)
      acc_z[rf] = __builtin_amdgcn_mfma_f32_16x16x32_f16(ah[rf], bz_, acc_z[rf], 0, 0, 0);
    #pragma unroll
    for (int rf = 0; rf < 4; ++rf)
      accn[rf] = __builtin_amdgcn_mfma_f32_16x16x32_f16(ah[rf], bn_, accn[rf], 0, 0, 0);
  };

  if constexpr (!INIT) {
    __syncthreads();
    // 96 h-half MFMAs (only gs/go + pointers live besides acc)
    #pragma unroll
    for (int ksgl = 0; ksgl < 8; ++ksgl) KS(HH_OFF, ksgl, 8 + ksgl, acc_nh);
  }

  // ---- combine: load x rows (L2-hot), consume immediately ----
  {
    #pragma unroll
    for (int c = 0; c < 2; ++c) {
      half8 hx;
      #pragma unroll
      for (int pq = 0; pq < 2; ++pq) {
        const int k0 = c * 128 + skc * 8 + pq * 4;
        const float4 a = *(const float4*)(pxa + k0);
        float4 v = a;
        if constexpr (GATES) {
          const float4 b4 = *(const float4*)(pxb + k0);
          v.x = gs * a.x + go * b4.x; v.y = gs * a.y + go * b4.y;
          v.z = gs * a.z + go * b4.z; v.w = gs * a.w + go * b4.w;
        }
        hx[pq * 4 + 0] = (_Float16)v.x; hx[pq * 4 + 1] = (_Float16)v.y;
        hx[pq * 4 + 2] = (_Float16)v.z; hx[pq * 4 + 3] = (_Float16)v.w;
      }
      *(half8*)(&lds[(srow * RSTR + XH_OFF + c * 256 + skc * 16) ^ swz]) = hx;
    }
  }
  __syncthreads();

  // 96 x-half MFMAs
  #pragma unroll
  for (int ksgl = 0; ksgl < 8; ++ksgl) KS(XH_OFF, ksgl, ksgl, acc_nx);

  // ---- epilogue: R4-exact, per-rf immediate compute + store ----
  const int col = w * 16 + lr;
  const float br = bih[col] + bhh[col];
  const float bz = bih[256 + col] + bhh[256 + col];
  const float bnx = bih[512 + col];
  const float bnh = bhh[512 + col];
  #pragma unroll
  for (int rf = 0; rf < 4; ++rf) {
    const int row0 = rb + rf * 16 + lq * 4;
    #pragma unroll
    for (int q = 0; q < 4; ++q) {
      const float r = sigf(acc_r[rf][q] + br);
      const float z = sigf(acc_z[rf][q] + bz);
      const float n = tanh_fast(acc_nx[rf][q] + bnx + r * (acc_nh[rf][q] + bnh));
      float hv = 0.0f;
      if constexpr (!INIT) hv = h[(row0 + q) * D_DIM + col];
      h[(row0 + q) * D_DIM + col] = (1.0f - z) * n + z * hv;
    }
  }
}

// per node row: dotA = nh.wnp[0:256], dotS = nh.wes[0:256], dotO = nh.weo[0:256]
__global__ __launch_bounds__(256) void dot3_kernel(
    const float* __restrict__ nh, const float* __restrict__ wnp,
    const float* __restrict__ wes, const float* __restrict__ weo,
    float* __restrict__ dA, float* __restrict__ dS, float* __restrict__ dO) {
  const int r = blockIdx.x * 4 + (threadIdx.x >> 6);
  const int l = threadIdx.x & 63;
  const float4 v = ((const float4*)(nh + r * D_DIM))[l];
  float p1 = dot4(v, ((const float4*)wnp)[l]);
  float p2 = dot4(v, ((const float4*)wes)[l]);
  float p3 = dot4(v, ((const float4*)weo)[l]);
  #pragma unroll
  for (int mm = 32; mm > 0; mm >>= 1) {
    p1 += __shfl_xor(p1, mm, 64);
    p2 += __shfl_xor(p2, mm, 64);
    p3 += __shfl_xor(p3, mm, 64);
  }
  if (l == 0) { dA[r] = p1; dS[r] = p2; dO[r] = p3; }
}

// node_msg[b,n] = sum over 62 incident edges of gN*eh,
// gN = sig(dotA[b,sub] + eh . w_node_pool[256:512]) computed inline.
__global__ __launch_bounds__(256) void node_msg_kernel(
    const float* __restrict__ eh, const float* __restrict__ wnp,
    const float* __restrict__ dotA, float* __restrict__ nmsg) {
  __shared__ float sh[3][256];
  const int nr = blockIdx.x;  // 0..4095
  const int b = nr >> 5;
  const int n = nr & 31;
  const int wv = threadIdx.x >> 6;
  const int l = threadIdx.x & 63;
  const int base = b * NEDGE;
  const float4 w1b = ((const float4*)(wnp + 256))[l];

  float4 acc = {0.f, 0.f, 0.f, 0.f};
  for (int k = wv; k < 62; k += 4) {
    int e, sub;
    if (k < 31) {             // out-edge (n -> *)
      e = base + n * 31 + k;
      sub = n;
    } else {                  // in-edge (i -> n)
      int i = k - 31;
      const int ip = (i < n) ? i : (i + 1);
      e = base + ip * 31 + ((n < ip) ? n : (n - 1));
      sub = ip;
    }
    const float4 ev = ((const float4*)(eh + e * D_DIM))[l];
    float p = dot4(ev, w1b);
    #pragma unroll
    for (int mm = 32; mm > 0; mm >>= 1) p += __shfl_xor(p, mm, 64);
    const float gN = sigf(dotA[b * NNODE + sub] + p);
    acc.x += gN * ev.x; acc.y += gN * ev.y; acc.z += gN * ev.z; acc.w += gN * ev.w;
  }
  if (wv > 0) *(float4*)(&sh[wv - 1][l * 4]) = acc;
  __syncthreads();
  if (wv == 0) {
    #pragma unroll
    for (int v = 0; v < 3; ++v) {
      const float4 o = *(const float4*)(&sh[v][l * 4]);
      acc.x += o.x; acc.y += o.y; acc.z += o.z; acc.w += o.w;
    }
    *(float4*)(nmsg + nr * D_DIM + l * 4) = acc;
  }
}

extern "C" void kernel_launch(void* const* d_in, const int* in_sizes, int n_in,
                              void* d_out, int out_size, void* d_ws, size_t ws_size,
                              hipStream_t stream) {
  const float* node_latents = (const float*)d_in[0];
  const float* edge_latents = (const float*)d_in[1];
  const float* node_Wih = (const float*)d_in[2];
  const float* node_Whh = (const float*)d_in[3];
  const float* node_bih = (const float*)d_in[4];
  const float* node_bhh = (const float*)d_in[5];
  const float* edge_Wih = (const float*)d_in[6];
  const float* edge_Whh = (const float*)d_in[7];
  const float* edge_bih = (const float*)d_in[8];
  const float* edge_bhh = (const float*)d_in[9];
  const float* w_node_pool = (const float*)d_in[10];
  const float* w_edge_sub = (const float*)d_in[11];
  const float* w_edge_obj = (const float*)d_in[12];

  float* nh = (float*)d_out;
  float* eh = (float*)d_out + NODE_ROWS * D_DIM;

  const int WPLANE = 48 * 16 * 64 * 8;  // 393216 f16 = 768KB
  _Float16* ph_n = (_Float16*)d_ws;
  _Float16* ph_e = ph_n + WPLANE;
  float* fw = (float*)(ph_e + WPLANE);
  float* dotA = fw; fw += NODE_ROWS;
  float* dotS = fw; fw += NODE_ROWS;
  float* dotO = fw; fw += NODE_ROWS;
  float* node_msg = fw; fw += NODE_ROWS * D_DIM;  // total ~5.7 MB

  dim3 pg(48, 16);
  pack_w<<<pg, 64, 0, stream>>>(node_Wih, node_Whh, ph_n);
  pack_w<<<pg, 64, 0, stream>>>(edge_Wih, edge_Whh, ph_e);

  gru_mfma<true, false><<<NODE_ROWS / BM, 1024, 0, stream>>>(
      node_latents, nullptr, nh, ph_n, node_bih, node_bhh,
      nullptr, nullptr, nullptr, nullptr);
  gru_mfma<true, false><<<EDGE_ROWS / BM, 1024, 0, stream>>>(
      edge_latents, nullptr, eh, ph_e, edge_bih, edge_bhh,
      nullptr, nullptr, nullptr, nullptr);

  for (int it = 0; it < 3; ++it) {
    dot3_kernel<<<NODE_ROWS / 4, 256, 0, stream>>>(nh, w_node_pool, w_edge_sub,
                                                   w_edge_obj, dotA, dotS, dotO);
    node_msg_kernel<<<NODE_ROWS, 256, 0, stream>>>(eh, w_node_pool, dotA, node_msg);
    gru_mfma<false, true><<<EDGE_ROWS / BM, 1024, 0, stream>>>(
        nullptr, nh, eh, ph_e, edge_bih, edge_bhh,
        w_edge_sub + 256, w_edge_obj + 256, dotS, dotO);
    gru_mfma<false, false><<<NODE_ROWS / BM, 1024, 0, stream>>>(
        node_msg, nullptr, nh, ph_n, node_bih, node_bhh,
        nullptr, nullptr, nullptr, nullptr);
  }
}